// Round 18
// baseline (1098.998 us; speedup 1.0000x reference)
//
#include <hip/hip_runtime.h>
#include <cmath>

// RouterCond fused, round 18: r17 + GEMM1 on mfma_f32_32x32x16_f16
// (half the MFMA instructions, 2382-2495 TF shape ceiling vs 2075).
// Geometry/staging/GEMM2/epilogue = r17-verbatim. C-layout per m74/m101:
// col=lane&31, row=(reg&3)+8*(reg>>2)+4*(lane>>5).
#define N_TOK 32768
#define D0    1024
#define DCC   512
#define DIN   1536
#define JD    3072
#define NE    64
#define BM    128
#define BJ    512
#define NJC   (JD/BJ)      // 6
#define NIT   48           // k-steps of 32
#define NTH   512
#define HS    36
#define EPSV  1e-9f

typedef _Float16 half8  __attribute__((ext_vector_type(8)));
typedef float    f32x4  __attribute__((ext_vector_type(4)));
typedef float    f32x16 __attribute__((ext_vector_type(16)));

// ---- LDS: A buf [pl2][koct4][row128] = 16KB x2; B buf [pl2][koct4][col512] = 64KB x2.
#define SZ_A  16384
#define SZ_B  65536
#define OFF_A 0
#define OFF_B 32768
#define LDS_TOTAL 163840
#define OFF_H    0                 // 8 x 9216 = 73728, aliases A+B0 (fenced)
#define OFF_LRED 73728
#define OFF_EPI  (73728 + 34816)

#define W1N   ((size_t)JD*DIN)
#define W2N   ((size_t)NE*JD)
#define XTN   ((size_t)N_TOK*DIN)
#define XT_G  (256*192*128)
#define W1T_G (192*3072)
#define W2T_G (384*64)

__device__ __forceinline__ f32x4 mfma16(half8 a, half8 b, f32x4 c) {
    return __builtin_amdgcn_mfma_f32_16x16x32_f16(a, b, c, 0, 0, 0);
}
__device__ __forceinline__ f32x16 mfma32(half8 a, half8 b, f32x16 c) {
    return __builtin_amdgcn_mfma_f32_32x32x16_f16(a, b, c, 0, 0, 0);
}

__device__ __forceinline__ void split8(const float4 v0, const float4 v1, half8& hh, half8& hl) {
    float f[8] = {v0.x, v0.y, v0.z, v0.w, v1.x, v1.y, v1.z, v1.w};
    #pragma unroll
    for (int i = 0; i < 8; ++i) {
        _Float16 h = (_Float16)f[i];
        hh[i] = h;
        hl[i] = (_Float16)(f[i] - (float)h);
    }
}

__device__ __forceinline__ void gload16(const void* g, void* l) {
    __builtin_amdgcn_global_load_lds(
        (const __attribute__((address_space(1))) unsigned int*)g,
        (__attribute__((address_space(3))) unsigned int*)l, 16, 0, 0);
}

// -------- presplit kernels (r16/r17-proven) --------
__global__ void presplit_w1t(const float* __restrict__ W1,
                             _Float16* __restrict__ hi, _Float16* __restrict__ lo) {
    int g = blockIdx.x * blockDim.x + threadIdx.x;
    if (g >= W1T_G) return;
    const int j  = g % JD;
    const int ko = g / JD;
    const float* src = W1 + (size_t)j * DIN + ko * 8;
    float4 v0 = *(const float4*)src;
    float4 v1 = *(const float4*)(src + 4);
    half8 h, l;
    split8(v0, v1, h, l);
    *(half8*)(hi + (size_t)g * 8) = h;
    *(half8*)(lo + (size_t)g * 8) = l;
}

__global__ void presplit_w2t(const float* __restrict__ W2,
                             _Float16* __restrict__ hi, _Float16* __restrict__ lo) {
    int g = blockIdx.x * blockDim.x + threadIdx.x;
    if (g >= W2T_G) return;
    const int e  = g & 63;
    const int jo = g >> 6;
    const float* src = W2 + (size_t)e * JD + jo * 8;
    float4 v0 = *(const float4*)src;
    float4 v1 = *(const float4*)(src + 4);
    half8 h, l;
    split8(v0, v1, h, l);
    *(half8*)(hi + (size_t)g * 8) = h;
    *(half8*)(lo + (size_t)g * 8) = l;
}

__global__ void presplit_xt(const float* __restrict__ inp, const float* __restrict__ cnd,
                            _Float16* __restrict__ hi, _Float16* __restrict__ lo) {
    int g = blockIdx.x * blockDim.x + threadIdx.x;
    if (g >= XT_G) return;
    const int r    = g & 127;
    const int ko   = (g >> 7) % 192;
    const int tile = g / (192 * 128);
    const int token = tile * 128 + r;
    const float* src = (ko < 128) ? (inp + (size_t)token * D0 + ko * 8)
                                  : (cnd + (size_t)token * DCC + (ko - 128) * 8);
    float4 v0 = *(const float4*)src;
    float4 v1 = *(const float4*)(src + 4);
    half8 h, l;
    split8(v0, v1, h, l);
    *(half8*)(hi + (size_t)g * 8) = h;
    *(half8*)(lo + (size_t)g * 8) = l;
}

// ================= v18 main kernel =================
__global__ __launch_bounds__(NTH, 1)
void router_v18(const _Float16* __restrict__ Xh, const _Float16* __restrict__ Xl,
                const _Float16* __restrict__ W1h, const _Float16* __restrict__ W1l,
                const _Float16* __restrict__ W2h, const _Float16* __restrict__ W2l,
                float* __restrict__ out_mask, float* __restrict__ out_topi,
                float* __restrict__ out_rp, float* __restrict__ out_probs)
{
    __shared__ __align__(16) char smem[LDS_TOTAL];

    const int tid  = threadIdx.x;
    const int lane = tid & 63;
    const int w    = tid >> 6;      // wave 0..7
    const int tg   = w >> 2;        // token half: rows tg*64..+63
    const int jg   = w & 3;         // j quarter (128 cols) / expert group (16)
    const int l15  = lane & 15;
    const int lg   = lane >> 4;     // 0..3 (GEMM2 k-oct)
    const int l31  = lane & 31;
    const int lh   = lane >> 5;     // 0..1 (32x32 k-half)
    const int blk  = blockIdx.x;
    const int t0   = blk * BM;

    // staging roles: plane = w>>2, koct = w&3 (r17-proven)
    const int spl = w >> 2;
    const int sko = w & 3;

    // GEMM1 32x32 frag byte offsets (hi plane; lo: A +8192, B +32768)
    int aoff[2][2], boff[2][4];
    #pragma unroll
    for (int s = 0; s < 2; ++s) {
        #pragma unroll
        for (int tf = 0; tf < 2; ++tf)
            aoff[s][tf] = ((s*2 + lh) * 128 + tg*64 + tf*32 + l31) * 16;
        #pragma unroll
        for (int jf = 0; jf < 4; ++jf)
            boff[s][jf] = ((s*2 + lh) * 512 + jg*128 + jf*32 + l31) * 16;
    }

    const f32x4 vzero4 = {0.f, 0.f, 0.f, 0.f};
    f32x4 lacc[4] = {vzero4, vzero4, vzero4, vzero4};   // 64 tok x 16 experts

    const _Float16* const Wbp = spl ? W1l : W1h;
    const _Float16* const Xbp = spl ? Xl  : Xh;
    const size_t xbase = (size_t)blk * 192 * 128;

    _Float16* const myHh = (_Float16*)(smem + OFF_H + w * 9216);
    _Float16* const myHl = myHh + 2304;

    for (int jc = 0; jc < NJC; ++jc) {
        f32x16 acc1[2][4];
        #pragma unroll
        for (int tf = 0; tf < 2; ++tf)
            #pragma unroll
            for (int jf = 0; jf < 4; ++jf)
                #pragma unroll
                for (int q = 0; q < 16; ++q) acc1[tf][jf][q] = 0.f;

        // ---- prologue: stage it=0 into buf0 (A: 2 gload16, B: 8 gload16)
        {
            const _Float16* asrc = Xbp + (xbase + (size_t)sko * 128) * 8;
            char* adst = smem + OFF_A + spl * 8192 + sko * 2048;
            gload16(asrc + (size_t)lane * 8, adst);
            gload16(asrc + (size_t)(64 + lane) * 8, adst + 1024);
            const _Float16* bsrc = Wbp + ((size_t)sko * JD + jc * BJ) * 8;
            char* bdst = smem + OFF_B + spl * 32768 + sko * 8192;
            #pragma unroll
            for (int q = 0; q < 8; ++q)
                gload16(bsrc + (size_t)(q * 64 + lane) * 8, bdst + q * 1024);
        }
        __syncthreads();

        for (int it = 0; it < NIT; ++it) {
            const int cur = it & 1, nxt = cur ^ 1;
            const bool more = (it + 1 < NIT);
            if (more) {   // zero-VALU staging of it+1 (r16/r17-proven)
                const _Float16* asrc = Xbp + (xbase + (size_t)((it + 1) * 4 + sko) * 128) * 8;
                char* adst = smem + OFF_A + nxt * SZ_A + spl * 8192 + sko * 2048;
                gload16(asrc + (size_t)lane * 8, adst);
                gload16(asrc + (size_t)(64 + lane) * 8, adst + 1024);
                const _Float16* bsrc = Wbp +
                    ((size_t)((it + 1) * 4 + sko) * JD + jc * BJ) * 8;
                char* bdst = smem + OFF_B + nxt * SZ_B + spl * 32768 + sko * 8192;
                #pragma unroll
                for (int q = 0; q < 8; ++q)
                    gload16(bsrc + (size_t)(q * 64 + lane) * 8, bdst + q * 1024);
            }
            const char* ab = smem + OFF_A + cur * SZ_A;
            const char* bb = smem + OFF_B + cur * SZ_B;
            #pragma unroll
            for (int s = 0; s < 2; ++s) {   // two k=16 steps
                half8 ah[2], al[2];
                #pragma unroll
                for (int tf = 0; tf < 2; ++tf) {
                    ah[tf] = *(const half8*)(ab + aoff[s][tf]);
                    al[tf] = *(const half8*)(ab + 8192 + aoff[s][tf]);
                }
                #pragma unroll
                for (int jf = 0; jf < 4; ++jf) {
                    half8 bh = *(const half8*)(bb + boff[s][jf]);
                    half8 bl = *(const half8*)(bb + 32768 + boff[s][jf]);
                    #pragma unroll
                    for (int tf = 0; tf < 2; ++tf) {
                        acc1[tf][jf] = mfma32(ah[tf], bh, acc1[tf][jf]);
                        acc1[tf][jf] = mfma32(ah[tf], bl, acc1[tf][jf]);
                        acc1[tf][jf] = mfma32(al[tf], bh, acc1[tf][jf]);
                    }
                }
            }
            __syncthreads();   // drains it+1 gloads (issued a full iter ago)
        }

        // ---- GELU + expert-split GEMM2: 4 rounds, round r consumes jf=r tile.
        // 32x32 C layout: tok = tf*32 + (reg&3)+8*(reg>>2)+4*lh, col(j) = l31.
        #pragma unroll
        for (int r = 0; r < 4; ++r) {
            #pragma unroll
            for (int tf = 0; tf < 2; ++tf)
                #pragma unroll
                for (int reg = 0; reg < 16; ++reg) {
                    const float v = acc1[tf][r][reg];
                    const float gv = 0.5f * v * (1.0f + erff(v * 0.70710678118654752f));
                    const _Float16 gh = (_Float16)gv;
                    const _Float16 gl = (_Float16)(gv - (float)gh);
                    const int tok = tf*32 + (reg & 3) + 8*(reg >> 2) + 4*lh;
                    const int o = tok * HS + l31;
                    myHh[o] = gh; myHl[o] = gl;
                }
            __syncthreads();
            #pragma unroll
            for (int s = 0; s < 4; ++s) {
                const _Float16* sh = (const _Float16*)(smem + OFF_H + (tg*4 + s) * 9216);
                const _Float16* sl = sh + 2304;
                const int jo = jc*64 + s*16 + r*4 + lg;
                const size_t wg = ((size_t)jo * 64 + jg*16 + l15) * 8;
                half8 b2h = *(const half8*)(W2h + wg);
                half8 b2l = *(const half8*)(W2l + wg);
                #pragma unroll
                for (int tf = 0; tf < 4; ++tf) {
                    const int o = (tf*16 + l15) * HS + lg*8;
                    half8 a2h = *(const half8*)(sh + o);
                    half8 a2l = *(const half8*)(sl + o);
                    lacc[tf] = mfma16(a2h, b2h, lacc[tf]);
                    lacc[tf] = mfma16(a2h, b2l, lacc[tf]);
                    lacc[tf] = mfma16(a2l, b2h, lacc[tf]);
                }
            }
            __syncthreads();
        }
    }

    // ---- epilogue (r9/r16/r17-proven; lacc is 16x16 layout, unchanged)
    float* const Lred = (float*)(smem + OFF_LRED);
    #pragma unroll
    for (int tf = 0; tf < 4; ++tf)
        #pragma unroll
        for (int rr = 0; rr < 4; ++rr)
            Lred[(tg*64 + tf*16 + lg*4 + rr) * 68 + jg*16 + l15] = lacc[tf][rr];
    __syncthreads();

    float* const mA   = (float*)(smem + OFF_EPI);
    float* const invA = mA + BM;
    int*   const i1A  = (int*)(invA + BM);
    int*   const i2A  = i1A + BM;
    float* const rp1A = (float*)(i2A + BM);
    float* const rp2A = rp1A + BM;

    if (tid < BM) {
        const float* row = Lred + tid * 68;
        float m = -3.402823466e38f;
        for (int e = 0; e < NE; ++e) m = fmaxf(m, row[e]);
        float s = 0.f, v1 = -3.402823466e38f, v2 = -3.402823466e38f;
        int i1 = 0, i2 = 0;
        for (int e = 0; e < NE; ++e) {
            const float v = row[e];
            s += expf(v - m);
            if (v > v1)      { v2 = v1; i2 = i1; v1 = v; i1 = e; }
            else if (v > v2) { v2 = v; i2 = e; }
        }
        const float inv = 1.f / s;
        const float p1 = fminf(expf(v1 - m) * inv + EPSV, 1.f - EPSV);
        const float p2 = fminf(expf(v2 - m) * inv + EPSV, 1.f - EPSV);
        mA[tid] = m; invA[tid] = inv; i1A[tid] = i1; i2A[tid] = i2;
        const float den = p1 + p2;
        rp1A[tid] = p1 / den; rp2A[tid] = p2 / den;
    }
    __syncthreads();

    for (int idx = tid; idx < BM * NE; idx += NTH) {
        const int r = idx >> 6, e = idx & 63;
        const size_t o = (size_t)(t0 + r) * NE + e;
        const float p = fminf(expf(Lred[r * 68 + e] - mA[r]) * invA[r] + EPSV, 1.f - EPSV);
        const int b1 = (e == i1A[r]), b2 = (e == i2A[r]);
        out_probs[o] = p;
        out_mask[o]  = (b1 | b2) ? 1.f : 0.f;
        out_rp[o]    = b1 ? rp1A[r] : (b2 ? rp2A[r] : 0.f);
    }
    if (tid < BM * 2) {
        const int r = tid >> 1, q = tid & 1;
        out_topi[(size_t)(t0 + r) * 2 + q] = (float)(q ? i2A[r] : i1A[r]);
    }
}

// ================= r9-style fallback (ws-small path, r16-proven) =================
#define FB_SZ_A  16384
#define FB_SZ_B  32768
#define FB_OFF_B 32768
#define FB_LDS   98304

__global__ __launch_bounds__(NTH, 1)
void router_v9fb(const float* __restrict__ inp, const float* __restrict__ cnd,
                 const _Float16* __restrict__ W1h, const _Float16* __restrict__ W1l,
                 const _Float16* __restrict__ W2h, const _Float16* __restrict__ W2l,
                 float* __restrict__ out_mask, float* __restrict__ out_topi,
                 float* __restrict__ out_rp, float* __restrict__ out_probs)
{
    __shared__ __align__(16) char smem[FB_LDS];
    const int tid  = threadIdx.x;
    const int lane = tid & 63;
    const int w    = tid >> 6;
    const int tg   = w >> 2;
    const int jg   = w & 3;
    const int l15  = lane & 15;
    const int lg   = lane >> 4;
    const int t0   = blockIdx.x * BM;
    const int akoct = w >> 1;
    const int arow  = (w & 1) * 64 + lane;
    const int bplane = w >> 2;
    const int bkoct  = w & 3;

    int aoff[4], boff[4];
    #pragma unroll
    for (int tf = 0; tf < 4; ++tf) aoff[tf] = (lg*128 + tg*64 + tf*16 + l15) * 16;
    #pragma unroll
    for (int jf = 0; jf < 4; ++jf) boff[jf] = (lg*256 + jg*64 + jf*16 + l15) * 16;

    const f32x4 vzero = {0.f, 0.f, 0.f, 0.f};
    f32x4 lacc[4] = {vzero, vzero, vzero, vzero};
    const float* const xrowA = inp + (size_t)(t0 + arow) * D0;
    const float* const xrowC = cnd + (size_t)(t0 + arow) * DCC;
    const _Float16* const Wbp = bplane ? W1l : W1h;
    _Float16* const myHh = (_Float16*)(smem + w * 9216);
    _Float16* const myHl = myHh + 2304;

    for (int jc = 0; jc < JD/256; ++jc) {
        f32x4 acc1[4][4];
        #pragma unroll
        for (int tf = 0; tf < 4; ++tf)
            #pragma unroll
            for (int jf = 0; jf < 4; ++jf) acc1[tf][jf] = vzero;
        {
            #pragma unroll
            for (int q = 0; q < 4; ++q) {
                const _Float16* src = Wbp + ((size_t)bkoct * JD + jc*256 + q*64 + lane) * 8;
                gload16(src, smem + FB_OFF_B + bplane*16384 + bkoct*4096 + q*1024);
            }
            const float* sx = xrowA + akoct * 8;
            float4 v0 = *(const float4*)sx;
            float4 v1 = *(const float4*)(sx + 4);
            half8 hh, hl;
            split8(v0, v1, hh, hl);
            const int g = (akoct*128 + arow) * 16;
            *(half8*)(smem + g) = hh;
            *(half8*)(smem + 8192 + g) = hl;
        }
        __syncthreads();
        for (int it = 0; it < NIT; ++it) {
            const int cur = it & 1, nxt = cur ^ 1;
            const bool more = (it + 1 < NIT);
            float4 xv0, xv1;
            if (more) {
                const int ko = (it + 1) * 4 + bkoct;
                #pragma unroll
                for (int q = 0; q < 4; ++q) {
                    const _Float16* src = Wbp + ((size_t)ko * JD + jc*256 + q*64 + lane) * 8;
                    gload16(src, smem + FB_OFF_B + nxt*FB_SZ_B + bplane*16384 + bkoct*4096 + q*1024);
                }
                const int k = (it + 1) * 32 + akoct * 8;
                const float* sx = (k < D0) ? (xrowA + k) : (xrowC + k - D0);
                xv0 = *(const float4*)sx;
                xv1 = *(const float4*)(sx + 4);
            }
            const char* ab = smem + cur*FB_SZ_A;
            const char* bb = smem + FB_OFF_B + cur*FB_SZ_B;
            half8 ah[4], al[4], bh[4], bl[4];
            #pragma unroll
            for (int tf = 0; tf < 4; ++tf) {
                ah[tf] = *(const half8*)(ab + aoff[tf]);
                al[tf] = *(const half8*)(ab + 8192 + aoff[tf]);
            }
            #pragma unroll
            for (int jf = 0; jf < 4; ++jf) {
                bh[jf] = *(const half8*)(bb + boff[jf]);
                bl[jf] = *(const half8*)(bb + 16384 + boff[jf]);
            }
            #pragma unroll
            for (int tf = 0; tf < 4; ++tf)
                #pragma unroll
                for (int jf = 0; jf < 4; ++jf) {
                    acc1[tf][jf] = mfma16(ah[tf], bh[jf], acc1[tf][jf]);
                    acc1[tf][jf] = mfma16(ah[tf], bl[jf], acc1[tf][jf]);
                    acc1[tf][jf] = mfma16(al[tf], bh[jf], acc1[tf][jf]);
                }
            if (more) {
                half8 hh, hl;
                split8(xv0, xv1, hh, hl);
                const int g = (akoct*128 + arow) * 16;
                *(half8*)(smem + nxt*FB_SZ_A + g) = hh;
                *(half8*)(smem + nxt*FB_SZ_A + 8192 + g) = hl;
            }
            __syncthreads();
        }
        #pragma unroll
        for (int r = 0; r < 2; ++r) {
            #pragma unroll
            for (int c = 0; c < 2; ++c) {
                const int jf = 2*r + c;
                #pragma unroll
                for (int tf = 0; tf < 4; ++tf)
                    #pragma unroll
                    for (int rr = 0; rr < 4; ++rr) {
                        const float v = acc1[tf][jf][rr];
                        const float gv = 0.5f * v * (1.0f + erff(v * 0.70710678118654752f));
                        const _Float16 gh = (_Float16)gv;
                        const _Float16 gl = (_Float16)(gv - (float)gh);
                        const int o = (tf*16 + lg*4 + rr) * HS + c*16 + l15;
                        myHh[o] = gh; myHl[o] = gl;
                    }
            }
            __syncthreads();
            #pragma unroll
            for (int s = 0; s < 4; ++s) {
                const _Float16* sh = (const _Float16*)(smem + (tg*4 + s) * 9216);
                const _Float16* sl = sh + 2304;
                const int jo = jc*32 + s*8 + r*4 + lg;
                const size_t wg = ((size_t)jo * 64 + jg*16 + l15) * 8;
                half8 b2h = *(const half8*)(W2h + wg);
                half8 b2l = *(const half8*)(W2l + wg);
                #pragma unroll
                for (int tf = 0; tf < 4; ++tf) {
                    const int o = (tf*16 + l15) * HS + lg*8;
                    half8 a2h = *(const half8*)(sh + o);
                    half8 a2l = *(const half8*)(sl + o);
                    lacc[tf] = mfma16(a2h, b2h, lacc[tf]);
                    lacc[tf] = mfma16(a2h, b2l, lacc[tf]);
                    lacc[tf] = mfma16(a2l, b2h, lacc[tf]);
                }
            }
            __syncthreads();
        }
    }
    float* const Lred = (float*)smem;
    #pragma unroll
    for (int tf = 0; tf < 4; ++tf)
        #pragma unroll
        for (int rr = 0; rr < 4; ++rr)
            Lred[(tg*64 + tf*16 + lg*4 + rr) * 68 + jg*16 + l15] = lacc[tf][rr];
    __syncthreads();
    float* const mA   = (float*)(smem + 36864);
    float* const invA = mA + BM;
    int*   const i1A  = (int*)(invA + BM);
    int*   const i2A  = i1A + BM;
    float* const rp1A = (float*)(i2A + BM);
    float* const rp2A = rp1A + BM;
    if (tid < BM) {
        const float* row = Lred + tid * 68;
        float m = -3.402823466e38f;
        for (int e = 0; e < NE; ++e) m = fmaxf(m, row[e]);
        float s = 0.f, v1 = -3.402823466e38f, v2 = -3.402823466e38f;
        int i1 = 0, i2 = 0;
        for (int e = 0; e < NE; ++e) {
            const float v = row[e];
            s += expf(v - m);
            if (v > v1)      { v2 = v1; i2 = i1; v1 = v; i1 = e; }
            else if (v > v2) { v2 = v; i2 = e; }
        }
        const float inv = 1.f / s;
        const float p1 = fminf(expf(v1 - m) * inv + EPSV, 1.f - EPSV);
        const float p2 = fminf(expf(v2 - m) * inv + EPSV, 1.f - EPSV);
        mA[tid] = m; invA[tid] = inv; i1A[tid] = i1; i2A[tid] = i2;
        const float den = p1 + p2;
        rp1A[tid] = p1 / den; rp2A[tid] = p2 / den;
    }
    __syncthreads();
    for (int idx = tid; idx < BM * NE; idx += NTH) {
        const int r = idx >> 6, e = idx & 63;
        const size_t o = (size_t)(t0 + r) * NE + e;
        const float p = fminf(expf(Lred[r * 68 + e] - mA[r]) * invA[r] + EPSV, 1.f - EPSV);
        const int b1 = (e == i1A[r]), b2 = (e == i2A[r]);
        out_probs[o] = p;
        out_mask[o]  = (b1 | b2) ? 1.f : 0.f;
        out_rp[o]    = b1 ? rp1A[r] : (b2 ? rp2A[r] : 0.f);
    }
    if (tid < BM * 2) {
        const int r = tid >> 1, q = tid & 1;
        out_topi[(size_t)(t0 + r) * 2 + q] = (float)(q ? i2A[r] : i1A[r]);
    }
}

extern "C" void kernel_launch(void* const* d_in, const int* in_sizes, int n_in,
                              void* d_out, int out_size, void* d_ws, size_t ws_size,
                              hipStream_t stream) {
    const float* inp = (const float*)d_in[0];
    const float* cnd = (const float*)d_in[1];
    const float* W1  = (const float*)d_in[2];
    const float* W2  = (const float*)d_in[3];

    float* out = (float*)d_out;
    const size_t NT = (size_t)N_TOK;
    float* out_mask  = out;
    float* out_topi  = out + NT * NE;
    float* out_rp    = out + NT * NE + NT * 2;
    float* out_probs = out + NT * NE + NT * 2 + NT * NE;

    const size_t V18_REQ = (2*XTN + 2*W1N + 2*W2N) * 2;   // ~221 MB
    if (ws_size >= V18_REQ) {
        _Float16* Xh  = (_Float16*)d_ws;
        _Float16* Xl  = Xh + XTN;
        _Float16* W1h = Xl + XTN;
        _Float16* W1l = W1h + W1N;
        _Float16* W2h = W1l + W1N;
        _Float16* W2l = W2h + W2N;
        hipLaunchKernelGGL(presplit_xt,  dim3(XT_G/256), dim3(256), 0, stream, inp, cnd, Xh, Xl);
        hipLaunchKernelGGL(presplit_w1t, dim3((W1T_G + 255)/256), dim3(256), 0, stream, W1, W1h, W1l);
        hipLaunchKernelGGL(presplit_w2t, dim3((W2T_G + 255)/256), dim3(256), 0, stream, W2, W2h, W2l);
        hipLaunchKernelGGL(router_v18, dim3(N_TOK / BM), dim3(NTH), 0, stream,
                           Xh, Xl, W1h, W1l, W2h, W2l,
                           out_mask, out_topi, out_rp, out_probs);
    } else {
        _Float16* W1h = (_Float16*)d_ws;
        _Float16* W1l = W1h + W1N;
        _Float16* W2h = W1l + W1N;
        _Float16* W2l = W2h + W2N;
        hipLaunchKernelGGL(presplit_w1t, dim3((W1T_G + 255)/256), dim3(256), 0, stream, W1, W1h, W1l);
        hipLaunchKernelGGL(presplit_w2t, dim3((W2T_G + 255)/256), dim3(256), 0, stream, W2, W2h, W2l);
        hipLaunchKernelGGL(router_v9fb, dim3(N_TOK / BM), dim3(NTH), 0, stream,
                           inp, cnd, W1h, W1l, W2h, W2l,
                           out_mask, out_topi, out_rp, out_probs);
    }
}

// Round 19
// 1087.810 us; speedup vs baseline: 1.0103x; 1.0103x over previous
//
#include <hip/hip_runtime.h>
#include <cmath>

// RouterCond fused, round 19: j-split 2-blocks/CU + A-from-global.
// Grid 512: block = (token-tile, j-half). LDS = B dbuf only (64 KB) -> two
// independent barrier domains per CU with NO W1-traffic penalty. A fragments
// read per-lane from pre-split Xt planes (L1-resident; no A LDS at all).
// Partial logits -> ws; tiny epilogue kernel reduces + softmax + top2.
// Fallback: r17 champion kernel (ws >= 221 MB proven by r15-r17).
#define N_TOK 32768
#define D0    1024
#define DCC   512
#define DIN   1536
#define JD    3072
#define NE    64
#define BM    128
#define BJ    512          // v17 fallback geometry
#define NJC   6
#define NIT   48
#define NTH   512
#define HS    36
#define EPSV  1e-9f

typedef _Float16 half8 __attribute__((ext_vector_type(8)));
typedef float    f32x4 __attribute__((ext_vector_type(4)));

#define W1N   ((size_t)JD*DIN)
#define W2N   ((size_t)NE*JD)
#define XTN   ((size_t)N_TOK*DIN)
#define XT_G  (256*192*128)
#define W1T_G (192*3072)
#define W2T_G (384*64)

__device__ __forceinline__ f32x4 mfma16(half8 a, half8 b, f32x4 c) {
    return __builtin_amdgcn_mfma_f32_16x16x32_f16(a, b, c, 0, 0, 0);
}

__device__ __forceinline__ void split8(const float4 v0, const float4 v1, half8& hh, half8& hl) {
    float f[8] = {v0.x, v0.y, v0.z, v0.w, v1.x, v1.y, v1.z, v1.w};
    #pragma unroll
    for (int i = 0; i < 8; ++i) {
        _Float16 h = (_Float16)f[i];
        hh[i] = h;
        hl[i] = (_Float16)(f[i] - (float)h);
    }
}

__device__ __forceinline__ void gload16(const void* g, void* l) {
    __builtin_amdgcn_global_load_lds(
        (const __attribute__((address_space(1))) unsigned int*)g,
        (__attribute__((address_space(3))) unsigned int*)l, 16, 0, 0);
}

// -------- presplit kernels (r16/r17-proven) --------
__global__ void presplit_w1t(const float* __restrict__ W1,
                             _Float16* __restrict__ hi, _Float16* __restrict__ lo) {
    int g = blockIdx.x * blockDim.x + threadIdx.x;
    if (g >= W1T_G) return;
    const int j  = g % JD;
    const int ko = g / JD;
    const float* src = W1 + (size_t)j * DIN + ko * 8;
    float4 v0 = *(const float4*)src;
    float4 v1 = *(const float4*)(src + 4);
    half8 h, l;
    split8(v0, v1, h, l);
    *(half8*)(hi + (size_t)g * 8) = h;
    *(half8*)(lo + (size_t)g * 8) = l;
}

__global__ void presplit_w2t(const float* __restrict__ W2,
                             _Float16* __restrict__ hi, _Float16* __restrict__ lo) {
    int g = blockIdx.x * blockDim.x + threadIdx.x;
    if (g >= W2T_G) return;
    const int e  = g & 63;
    const int jo = g >> 6;
    const float* src = W2 + (size_t)e * JD + jo * 8;
    float4 v0 = *(const float4*)src;
    float4 v1 = *(const float4*)(src + 4);
    half8 h, l;
    split8(v0, v1, h, l);
    *(half8*)(hi + (size_t)g * 8) = h;
    *(half8*)(lo + (size_t)g * 8) = l;
}

__global__ void presplit_xt(const float* __restrict__ inp, const float* __restrict__ cnd,
                            _Float16* __restrict__ hi, _Float16* __restrict__ lo) {
    int g = blockIdx.x * blockDim.x + threadIdx.x;
    if (g >= XT_G) return;
    const int r    = g & 127;
    const int ko   = (g >> 7) % 192;
    const int tile = g / (192 * 128);
    const int token = tile * 128 + r;
    const float* src = (ko < 128) ? (inp + (size_t)token * D0 + ko * 8)
                                  : (cnd + (size_t)token * DCC + (ko - 128) * 8);
    float4 v0 = *(const float4*)src;
    float4 v1 = *(const float4*)(src + 4);
    half8 h, l;
    split8(v0, v1, h, l);
    *(half8*)(hi + (size_t)g * 8) = h;
    *(half8*)(lo + (size_t)g * 8) = l;
}

// ================= v19 main kernel: j-split, 2 blocks/CU =================
__global__ __launch_bounds__(NTH, 2)
void router_v19(const _Float16* __restrict__ Xh, const _Float16* __restrict__ Xl,
                const _Float16* __restrict__ W1h, const _Float16* __restrict__ W1l,
                const _Float16* __restrict__ W2h, const _Float16* __restrict__ W2l,
                float* __restrict__ partial)
{
    __shared__ __align__(16) char smem[65536];   // B dbuf 2x32KB; H aliases

    const int tid  = threadIdx.x;
    const int lane = tid & 63;
    const int w    = tid >> 6;      // wave 0..7
    const int tg   = w >> 2;        // token half: rows tg*64..+63
    const int jg   = w & 3;         // j quarter (64 cols) / expert group (16)
    const int l15  = lane & 15;
    const int lg   = lane >> 4;     // k-oct 0..3
    const int tile = blockIdx.x >> 1;
    const int half = blockIdx.x & 1;
    const int jcol0 = half * 1536;

    // B staging roles (r9-proven): wave -> (plane, koct)
    const int bplane = w >> 2;
    const int bkoct  = w & 3;

    int boff[4];
    #pragma unroll
    for (int jf = 0; jf < 4; ++jf)
        boff[jf] = (lg*256 + jg*64 + jf*16 + l15) * 16;

    // A per-lane base pointers into pre-split Xt tile planes (lo = +XTN)
    const _Float16* baseA[4];
    #pragma unroll
    for (int tf = 0; tf < 4; ++tf)
        baseA[tf] = Xh + ((size_t)tile * 192 * 128 + tg*64 + tf*16 + l15) * 8;

    const f32x4 vzero = {0.f, 0.f, 0.f, 0.f};
    f32x4 lacc[4] = {vzero, vzero, vzero, vzero};   // 64 tok x 16 experts (partial)

    const _Float16* const Wbp = bplane ? W1l : W1h;

    for (int jc = 0; jc < 6; ++jc) {
        f32x4 acc1[4][4];
        #pragma unroll
        for (int tf = 0; tf < 4; ++tf)
            #pragma unroll
            for (int jf = 0; jf < 4; ++jf) acc1[tf][jf] = vzero;

        {   // prologue: stage B(it=0) into buf0 (4 gload16/wave)
            const _Float16* src = Wbp + ((size_t)bkoct * JD + jcol0 + jc*256) * 8;
            char* dst = smem + (bplane*4 + bkoct) * 4096;
            #pragma unroll
            for (int q = 0; q < 4; ++q)
                gload16(src + (size_t)(q*64 + lane) * 8, dst + q * 1024);
        }
        __syncthreads();

        for (int it = 0; it < NIT; ++it) {
            // A frags: direct per-lane global loads (L1-broadcast across jg quads)
            half8 ah[4], al[4];
            const int aoffh = (it*4 + lg) * 1024;   // halves
            #pragma unroll
            for (int tf = 0; tf < 4; ++tf) {
                ah[tf] = *(const half8*)(baseA[tf] + aoffh);
                al[tf] = *(const half8*)(baseA[tf] + XTN + aoffh);
            }
            __builtin_amdgcn_sched_barrier(0);   // A issued before B gloads
            if (it + 1 < NIT) {                  // stage B(it+1) into other buf
                const _Float16* src = Wbp +
                    ((size_t)((it+1)*4 + bkoct) * JD + jcol0 + jc*256) * 8;
                char* dst = smem + ((it+1) & 1) * 32768 + (bplane*4 + bkoct) * 4096;
                #pragma unroll
                for (int q = 0; q < 4; ++q)
                    gload16(src + (size_t)(q*64 + lane) * 8, dst + q * 1024);
            }
            const char* bb = smem + (it & 1) * 32768;
            half8 bh[4], bl[4];
            #pragma unroll
            for (int jf = 0; jf < 4; ++jf) {
                bh[jf] = *(const half8*)(bb + boff[jf]);
                bl[jf] = *(const half8*)(bb + 16384 + boff[jf]);
            }
            #pragma unroll
            for (int tf = 0; tf < 4; ++tf)
                #pragma unroll
                for (int jf = 0; jf < 4; ++jf) {
                    acc1[tf][jf] = mfma16(ah[tf], bh[jf], acc1[tf][jf]);
                    acc1[tf][jf] = mfma16(ah[tf], bl[jf], acc1[tf][jf]);
                    acc1[tf][jf] = mfma16(al[tf], bh[jf], acc1[tf][jf]);
                }
            __syncthreads();
        }

        // ---- GELU + expert-split GEMM2; H slabs (8 x 8KB) alias B bufs.
        // slab: Hh [64 tok][64 B] XOR-swizzled (tok&3)<<4; Hl at +4096.
        char* const slab = smem + w * 8192;
        #pragma unroll
        for (int r = 0; r < 2; ++r) {
            #pragma unroll
            for (int c = 0; c < 2; ++c) {
                const int jf = 2*r + c;
                #pragma unroll
                for (int tf = 0; tf < 4; ++tf)
                    #pragma unroll
                    for (int rr = 0; rr < 4; ++rr) {
                        const float v = acc1[tf][jf][rr];
                        const float gv = 0.5f * v * (1.0f + erff(v * 0.70710678118654752f));
                        const _Float16 gh = (_Float16)gv;
                        const _Float16 gl = (_Float16)(gv - (float)gh);
                        const int tok = tf*16 + lg*4 + rr;
                        int ob = tok*64 + (c*16 + l15)*2;
                        ob ^= ((tok & 3) << 4);
                        *(_Float16*)(slab + ob) = gh;
                        *(_Float16*)(slab + 4096 + ob) = gl;
                    }
            }
            __syncthreads();
            #pragma unroll
            for (int s = 0; s < 4; ++s) {
                const char* sh = smem + (tg*4 + s) * 8192;
                const int jo = half*192 + jc*32 + s*8 + r*4 + lg;
                const size_t wg = ((size_t)jo * 64 + jg*16 + l15) * 8;
                half8 b2h = *(const half8*)(W2h + wg);
                half8 b2l = *(const half8*)(W2l + wg);
                #pragma unroll
                for (int tf = 0; tf < 4; ++tf) {
                    const int row = tf*16 + l15;
                    int rb = row*64 + lg*16;
                    rb ^= ((row & 3) << 4);
                    half8 a2h = *(const half8*)(sh + rb);
                    half8 a2l = *(const half8*)(sh + 4096 + rb);
                    lacc[tf] = mfma16(a2h, b2h, lacc[tf]);
                    lacc[tf] = mfma16(a2h, b2l, lacc[tf]);
                    lacc[tf] = mfma16(a2l, b2h, lacc[tf]);
                }
            }
            __syncthreads();
        }
    }

    // ---- write partial logits (this j-half) to ws
    float* pp = partial + (size_t)(half*256 + tile) * 8192;
    #pragma unroll
    for (int tf = 0; tf < 4; ++tf)
        #pragma unroll
        for (int rr = 0; rr < 4; ++rr)
            pp[(tg*64 + tf*16 + lg*4 + rr) * 64 + jg*16 + l15] = lacc[tf][rr];
}

// ================= epilogue: reduce halves + softmax + top-2 =================
__global__ __launch_bounds__(256, 4)
void router_fin(const float* __restrict__ partial,
                float* __restrict__ out_mask, float* __restrict__ out_topi,
                float* __restrict__ out_rp, float* __restrict__ out_probs)
{
    __shared__ float L[128 * 68];
    __shared__ float mA[128], invA[128], rp1A[128], rp2A[128];
    __shared__ int   i1A[128], i2A[128];

    const int tid  = threadIdx.x;
    const int tile = blockIdx.x;
    const int t0   = tile * 128;
    const float4* pA = (const float4*)(partial + (size_t)tile * 8192);
    const float4* pB = (const float4*)(partial + (size_t)(256 + tile) * 8192);

    for (int idx = tid; idx < 2048; idx += 256) {
        float4 a = pA[idx], b = pB[idx];
        const int tok = idx >> 4, q = idx & 15;
        float* d = &L[tok * 68 + q * 4];
        d[0] = a.x + b.x; d[1] = a.y + b.y; d[2] = a.z + b.z; d[3] = a.w + b.w;
    }
    __syncthreads();

    if (tid < 128) {
        const float* row = L + tid * 68;
        float m = -3.402823466e38f;
        for (int e = 0; e < NE; ++e) m = fmaxf(m, row[e]);
        float s = 0.f, v1 = -3.402823466e38f, v2 = -3.402823466e38f;
        int i1 = 0, i2 = 0;
        for (int e = 0; e < NE; ++e) {
            const float v = row[e];
            s += expf(v - m);
            if (v > v1)      { v2 = v1; i2 = i1; v1 = v; i1 = e; }
            else if (v > v2) { v2 = v; i2 = e; }
        }
        const float inv = 1.f / s;
        const float p1 = fminf(expf(v1 - m) * inv + EPSV, 1.f - EPSV);
        const float p2 = fminf(expf(v2 - m) * inv + EPSV, 1.f - EPSV);
        mA[tid] = m; invA[tid] = inv; i1A[tid] = i1; i2A[tid] = i2;
        const float den = p1 + p2;
        rp1A[tid] = p1 / den; rp2A[tid] = p2 / den;
    }
    __syncthreads();

    for (int idx = tid; idx < 128 * NE; idx += 256) {
        const int r = idx >> 6, e = idx & 63;
        const size_t o = (size_t)(t0 + r) * NE + e;
        const float p = fminf(expf(L[r * 68 + e] - mA[r]) * invA[r] + EPSV, 1.f - EPSV);
        const int b1 = (e == i1A[r]), b2 = (e == i2A[r]);
        out_probs[o] = p;
        out_mask[o]  = (b1 | b2) ? 1.f : 0.f;
        out_rp[o]    = b1 ? rp1A[r] : (b2 ? rp2A[r] : 0.f);
    }
    {
        const int r = tid >> 1, q = tid & 1;   // 256 threads = 128 tokens x 2
        out_topi[(size_t)(t0 + r) * 2 + q] = (float)(q ? i2A[r] : i1A[r]);
    }
}

// ================= v17 fallback (champion, r17-verbatim) =================
#define SZ_A  16384
#define SZ_B  65536
#define OFF_A 0
#define OFF_B 32768
#define LDS_TOTAL 163840
#define OFF_H    0
#define OFF_LRED 73728
#define OFF_EPI  (73728 + 34816)

__global__ __launch_bounds__(NTH, 1)
void router_v17(const _Float16* __restrict__ Xh, const _Float16* __restrict__ Xl,
                const _Float16* __restrict__ W1h, const _Float16* __restrict__ W1l,
                const _Float16* __restrict__ W2h, const _Float16* __restrict__ W2l,
                float* __restrict__ out_mask, float* __restrict__ out_topi,
                float* __restrict__ out_rp, float* __restrict__ out_probs)
{
    __shared__ __align__(16) char smem[LDS_TOTAL];

    const int tid  = threadIdx.x;
    const int lane = tid & 63;
    const int w    = tid >> 6;
    const int tg   = w >> 2;
    const int jg   = w & 3;
    const int l15  = lane & 15;
    const int lg   = lane >> 4;
    const int blk  = blockIdx.x;
    const int t0   = blk * BM;

    const int spl = w >> 2;
    const int sko = w & 3;

    int aoff[4], boff[8];
    #pragma unroll
    for (int tf = 0; tf < 4; ++tf) aoff[tf] = (lg*128 + tg*64 + tf*16 + l15) * 16;
    #pragma unroll
    for (int jf = 0; jf < 8; ++jf) boff[jf] = lg*8192 + (jg*128 + jf*16 + l15) * 16;

    const f32x4 vzero = {0.f, 0.f, 0.f, 0.f};
    f32x4 lacc[4] = {vzero, vzero, vzero, vzero};

    const _Float16* const Wbp = spl ? W1l : W1h;
    const _Float16* const Xbp = spl ? Xl  : Xh;
    const size_t xbase = (size_t)blk * 192 * 128;

    _Float16* const myHh = (_Float16*)(smem + OFF_H + w * 9216);
    _Float16* const myHl = myHh + 2304;

    for (int jc = 0; jc < NJC; ++jc) {
        f32x4 acc1[4][8];
        #pragma unroll
        for (int tf = 0; tf < 4; ++tf)
            #pragma unroll
            for (int jf = 0; jf < 8; ++jf) acc1[tf][jf] = vzero;

        {
            const _Float16* asrc = Xbp + (xbase + (size_t)sko * 128) * 8;
            char* adst = smem + OFF_A + spl * 8192 + sko * 2048;
            gload16(asrc + (size_t)lane * 8, adst);
            gload16(asrc + (size_t)(64 + lane) * 8, adst + 1024);
            const _Float16* bsrc = Wbp + ((size_t)sko * JD + jc * BJ) * 8;
            char* bdst = smem + OFF_B + spl * 32768 + sko * 8192;
            #pragma unroll
            for (int q = 0; q < 8; ++q)
                gload16(bsrc + (size_t)(q * 64 + lane) * 8, bdst + q * 1024);
        }
        __syncthreads();

        for (int it = 0; it < NIT; ++it) {
            const int cur = it & 1, nxt = cur ^ 1;
            const bool more = (it + 1 < NIT);
            if (more) {
                const _Float16* asrc = Xbp + (xbase + (size_t)((it + 1) * 4 + sko) * 128) * 8;
                char* adst = smem + OFF_A + nxt * SZ_A + spl * 8192 + sko * 2048;
                gload16(asrc + (size_t)lane * 8, adst);
                gload16(asrc + (size_t)(64 + lane) * 8, adst + 1024);
                const _Float16* bsrc = Wbp +
                    ((size_t)((it + 1) * 4 + sko) * JD + jc * BJ) * 8;
                char* bdst = smem + OFF_B + nxt * SZ_B + spl * 32768 + sko * 8192;
                #pragma unroll
                for (int q = 0; q < 8; ++q)
                    gload16(bsrc + (size_t)(q * 64 + lane) * 8, bdst + q * 1024);
            }
            const char* ab = smem + OFF_A + cur * SZ_A;
            const char* bb = smem + OFF_B + cur * SZ_B;
            half8 ah[4], al[4];
            #pragma unroll
            for (int tf = 0; tf < 4; ++tf) {
                ah[tf] = *(const half8*)(ab + aoff[tf]);
                al[tf] = *(const half8*)(ab + 8192 + aoff[tf]);
            }
            #pragma unroll
            for (int jf = 0; jf < 8; ++jf) {
                half8 bh = *(const half8*)(bb + boff[jf]);
                half8 bl = *(const half8*)(bb + 32768 + boff[jf]);
                #pragma unroll
                for (int tf = 0; tf < 4; ++tf) {
                    acc1[tf][jf] = mfma16(ah[tf], bh, acc1[tf][jf]);
                    acc1[tf][jf] = mfma16(ah[tf], bl, acc1[tf][jf]);
                    acc1[tf][jf] = mfma16(al[tf], bh, acc1[tf][jf]);
                }
            }
            __syncthreads();
        }

        #pragma unroll
        for (int r = 0; r < 4; ++r) {
            #pragma unroll
            for (int c = 0; c < 2; ++c) {
                const int jf = 2*r + c;
                #pragma unroll
                for (int tf = 0; tf < 4; ++tf)
                    #pragma unroll
                    for (int rr = 0; rr < 4; ++rr) {
                        const float v = acc1[tf][jf][rr];
                        const float gv = 0.5f * v * (1.0f + erff(v * 0.70710678118654752f));
                        const _Float16 gh = (_Float16)gv;
                        const _Float16 gl = (_Float16)(gv - (float)gh);
                        const int o = (tf*16 + lg*4 + rr) * HS + c*16 + l15;
                        myHh[o] = gh; myHl[o] = gl;
                    }
            }
            __syncthreads();
            #pragma unroll
            for (int s = 0; s < 4; ++s) {
                const _Float16* sh = (const _Float16*)(smem + OFF_H + (tg*4 + s) * 9216);
                const _Float16* sl = sh + 2304;
                const int jo = jc*64 + s*16 + r*4 + lg;
                const size_t wg = ((size_t)jo * 64 + jg*16 + l15) * 8;
                half8 b2h = *(const half8*)(W2h + wg);
                half8 b2l = *(const half8*)(W2l + wg);
                #pragma unroll
                for (int tf = 0; tf < 4; ++tf) {
                    const int o = (tf*16 + l15) * HS + lg*8;
                    half8 a2h = *(const half8*)(sh + o);
                    half8 a2l = *(const half8*)(sl + o);
                    lacc[tf] = mfma16(a2h, b2h, lacc[tf]);
                    lacc[tf] = mfma16(a2h, b2l, lacc[tf]);
                    lacc[tf] = mfma16(a2l, b2h, lacc[tf]);
                }
            }
            __syncthreads();
        }
    }

    float* const Lred = (float*)(smem + OFF_LRED);
    #pragma unroll
    for (int tf = 0; tf < 4; ++tf)
        #pragma unroll
        for (int rr = 0; rr < 4; ++rr)
            Lred[(tg*64 + tf*16 + lg*4 + rr) * 68 + jg*16 + l15] = lacc[tf][rr];
    __syncthreads();

    float* const mA   = (float*)(smem + OFF_EPI);
    float* const invA = mA + BM;
    int*   const i1A  = (int*)(invA + BM);
    int*   const i2A  = i1A + BM;
    float* const rp1A = (float*)(i2A + BM);
    float* const rp2A = rp1A + BM;

    if (tid < BM) {
        const float* row = Lred + tid * 68;
        float m = -3.402823466e38f;
        for (int e = 0; e < NE; ++e) m = fmaxf(m, row[e]);
        float s = 0.f, v1 = -3.402823466e38f, v2 = -3.402823466e38f;
        int i1 = 0, i2 = 0;
        for (int e = 0; e < NE; ++e) {
            const float v = row[e];
            s += expf(v - m);
            if (v > v1)      { v2 = v1; i2 = i1; v1 = v; i1 = e; }
            else if (v > v2) { v2 = v; i2 = e; }
        }
        const float inv = 1.f / s;
        const float p1 = fminf(expf(v1 - m) * inv + EPSV, 1.f - EPSV);
        const float p2 = fminf(expf(v2 - m) * inv + EPSV, 1.f - EPSV);
        mA[tid] = m; invA[tid] = inv; i1A[tid] = i1; i2A[tid] = i2;
        const float den = p1 + p2;
        rp1A[tid] = p1 / den; rp2A[tid] = p2 / den;
    }
    __syncthreads();

    for (int idx = tid; idx < BM * NE; idx += NTH) {
        const int r = idx >> 6, e = idx & 63;
        const size_t o = (size_t)(t0 + r) * NE + e;
        const float p = fminf(expf(Lred[r * 68 + e] - mA[r]) * invA[r] + EPSV, 1.f - EPSV);
        const int b1 = (e == i1A[r]), b2 = (e == i2A[r]);
        out_probs[o] = p;
        out_mask[o]  = (b1 | b2) ? 1.f : 0.f;
        out_rp[o]    = b1 ? rp1A[r] : (b2 ? rp2A[r] : 0.f);
    }
    if (tid < BM * 2) {
        const int r = tid >> 1, q = tid & 1;
        out_topi[(size_t)(t0 + r) * 2 + q] = (float)(q ? i2A[r] : i1A[r]);
    }
}

extern "C" void kernel_launch(void* const* d_in, const int* in_sizes, int n_in,
                              void* d_out, int out_size, void* d_ws, size_t ws_size,
                              hipStream_t stream) {
    const float* inp = (const float*)d_in[0];
    const float* cnd = (const float*)d_in[1];
    const float* W1  = (const float*)d_in[2];
    const float* W2  = (const float*)d_in[3];

    float* out = (float*)d_out;
    const size_t NT = (size_t)N_TOK;
    float* out_mask  = out;
    float* out_topi  = out + NT * NE;
    float* out_rp    = out + NT * NE + NT * 2;
    float* out_probs = out + NT * NE + NT * 2 + NT * NE;

    const size_t BASE_REQ = (2*XTN + 2*W1N + 2*W2N) * 2;        // ~221.0 MB
    const size_t PART_B   = (size_t)512 * 8192 * 4;             // 16.8 MB
    _Float16* Xh  = (_Float16*)d_ws;
    _Float16* Xl  = Xh + XTN;
    _Float16* W1h = Xl + XTN;
    _Float16* W1l = W1h + W1N;
    _Float16* W2h = W1l + W1N;
    _Float16* W2l = W2h + W2N;

    hipLaunchKernelGGL(presplit_xt,  dim3(XT_G/256), dim3(256), 0, stream, inp, cnd, Xh, Xl);
    hipLaunchKernelGGL(presplit_w1t, dim3((W1T_G + 255)/256), dim3(256), 0, stream, W1, W1h, W1l);
    hipLaunchKernelGGL(presplit_w2t, dim3((W2T_G + 255)/256), dim3(256), 0, stream, W2, W2h, W2l);

    if (ws_size >= BASE_REQ + PART_B) {
        float* partial = (float*)((char*)d_ws + BASE_REQ);
        hipLaunchKernelGGL(router_v19, dim3(512), dim3(NTH), 0, stream,
                           Xh, Xl, W1h, W1l, W2h, W2l, partial);
        hipLaunchKernelGGL(router_fin, dim3(256), dim3(256), 0, stream,
                           partial, out_mask, out_topi, out_rp, out_probs);
    } else {
        hipLaunchKernelGGL(router_v17, dim3(N_TOK / BM), dim3(NTH), 0, stream,
                           Xh, Xl, W1h, W1l, W2h, W2l,
                           out_mask, out_topi, out_rp, out_probs);
    }
}

// Round 20
// 1024.693 us; speedup vs baseline: 1.0725x; 1.0616x over previous
//
#include <hip/hip_runtime.h>
#include <cmath>

// RouterCond fused, FINAL (round 20): restore round-17 champion verbatim.
// Structure: x/W1/W2 pre-split to fp16 hi/lo planes in ws (fp16x2-split MFMA
// emulates fp32-accuracy products: 3x mfma_f32_16x16x32_f16 per k-step);
// zero-VALU staging via contiguous global_load_lds (koct-major granule layout,
// conflict-free b128 frag reads); 64x128 wave tiles (BM=128, BJ=512, NJC=6);
// A dbuf 32KB + B dbuf 128KB = 160 KiB LDS; expert-split GEMM2 through
// wave-private H slabs; fused softmax/top-2 epilogue.
// Proven: 1026 us timed / 967 us profiled, MfmaUtil 45.1%, no spill (r17).
#define N_TOK 32768
#define D0    1024
#define DCC   512
#define DIN   1536
#define JD    3072
#define NE    64
#define BM    128
#define BJ    512
#define NJC   (JD/BJ)      // 6
#define NIT   48           // k-steps of 32
#define NTH   512
#define HS    36
#define EPSV  1e-9f

typedef _Float16 half8 __attribute__((ext_vector_type(8)));
typedef float    f32x4 __attribute__((ext_vector_type(4)));

// ---- LDS: A buf [pl2][koct4][row128] granules = 16KB x2.
//      B buf [pl2][koct4][col512] granules = 64KB x2. Total 160 KiB.
#define SZ_A  16384
#define SZ_B  65536
#define OFF_A 0                    // A bufs: 0, 16384
#define OFF_B 32768                // B bufs: 32768, 98304
#define LDS_TOTAL 163840
#define OFF_H    0                 // 8 x 9216 = 73728, aliases A+B0 (fenced)
#define OFF_LRED 73728             // [128][68] f32 = 34816
#define OFF_EPI  (73728 + 34816)

#define W1N   ((size_t)JD*DIN)
#define W2N   ((size_t)NE*JD)
#define XTN   ((size_t)N_TOK*DIN)
#define XT_G  (256*192*128)
#define W1T_G (192*3072)
#define W2T_G (384*64)

__device__ __forceinline__ f32x4 mfma16(half8 a, half8 b, f32x4 c) {
    return __builtin_amdgcn_mfma_f32_16x16x32_f16(a, b, c, 0, 0, 0);
}

__device__ __forceinline__ void split8(const float4 v0, const float4 v1, half8& hh, half8& hl) {
    float f[8] = {v0.x, v0.y, v0.z, v0.w, v1.x, v1.y, v1.z, v1.w};
    #pragma unroll
    for (int i = 0; i < 8; ++i) {
        _Float16 h = (_Float16)f[i];
        hh[i] = h;
        hl[i] = (_Float16)(f[i] - (float)h);
    }
}

__device__ __forceinline__ void gload16(const void* g, void* l) {
    __builtin_amdgcn_global_load_lds(
        (const __attribute__((address_space(1))) unsigned int*)g,
        (__attribute__((address_space(3))) unsigned int*)l, 16, 0, 0);
}

// -------- presplit kernels (r16/r17-proven) --------
__global__ void presplit_w1t(const float* __restrict__ W1,
                             _Float16* __restrict__ hi, _Float16* __restrict__ lo) {
    int g = blockIdx.x * blockDim.x + threadIdx.x;
    if (g >= W1T_G) return;
    const int j  = g % JD;
    const int ko = g / JD;
    const float* src = W1 + (size_t)j * DIN + ko * 8;
    float4 v0 = *(const float4*)src;
    float4 v1 = *(const float4*)(src + 4);
    half8 h, l;
    split8(v0, v1, h, l);
    *(half8*)(hi + (size_t)g * 8) = h;
    *(half8*)(lo + (size_t)g * 8) = l;
}

__global__ void presplit_w2t(const float* __restrict__ W2,
                             _Float16* __restrict__ hi, _Float16* __restrict__ lo) {
    int g = blockIdx.x * blockDim.x + threadIdx.x;
    if (g >= W2T_G) return;
    const int e  = g & 63;
    const int jo = g >> 6;
    const float* src = W2 + (size_t)e * JD + jo * 8;
    float4 v0 = *(const float4*)src;
    float4 v1 = *(const float4*)(src + 4);
    half8 h, l;
    split8(v0, v1, h, l);
    *(half8*)(hi + (size_t)g * 8) = h;
    *(half8*)(lo + (size_t)g * 8) = l;
}

__global__ void presplit_xt(const float* __restrict__ inp, const float* __restrict__ cnd,
                            _Float16* __restrict__ hi, _Float16* __restrict__ lo) {
    int g = blockIdx.x * blockDim.x + threadIdx.x;
    if (g >= XT_G) return;
    const int r    = g & 127;
    const int ko   = (g >> 7) % 192;
    const int tile = g / (192 * 128);
    const int token = tile * 128 + r;
    const float* src = (ko < 128) ? (inp + (size_t)token * D0 + ko * 8)
                                  : (cnd + (size_t)token * DCC + (ko - 128) * 8);
    float4 v0 = *(const float4*)src;
    float4 v1 = *(const float4*)(src + 4);
    half8 h, l;
    split8(v0, v1, h, l);
    *(half8*)(hi + (size_t)g * 8) = h;
    *(half8*)(lo + (size_t)g * 8) = l;
}

// ================= main kernel (r17 champion) =================
__global__ __launch_bounds__(NTH, 1)
void router_v17(const _Float16* __restrict__ Xh, const _Float16* __restrict__ Xl,
                const _Float16* __restrict__ W1h, const _Float16* __restrict__ W1l,
                const _Float16* __restrict__ W2h, const _Float16* __restrict__ W2l,
                float* __restrict__ out_mask, float* __restrict__ out_topi,
                float* __restrict__ out_rp, float* __restrict__ out_probs)
{
    __shared__ __align__(16) char smem[LDS_TOTAL];

    const int tid  = threadIdx.x;
    const int lane = tid & 63;
    const int w    = tid >> 6;      // wave 0..7
    const int tg   = w >> 2;        // token half: rows tg*64..+63
    const int jg   = w & 3;         // j quarter (128 cols) / expert group (16)
    const int l15  = lane & 15;
    const int lg   = lane >> 4;     // k-oct 0..3
    const int blk  = blockIdx.x;
    const int t0   = blk * BM;

    // staging roles (A and B): plane = w>>2, koct = w&3
    const int spl = w >> 2;
    const int sko = w & 3;

    // frag byte offsets (hi plane; lo: A +8192, B +32768)
    int aoff[4], boff[8];
    #pragma unroll
    for (int tf = 0; tf < 4; ++tf) aoff[tf] = (lg*128 + tg*64 + tf*16 + l15) * 16;
    #pragma unroll
    for (int jf = 0; jf < 8; ++jf) boff[jf] = lg*8192 + (jg*128 + jf*16 + l15) * 16;

    const f32x4 vzero = {0.f, 0.f, 0.f, 0.f};
    f32x4 lacc[4] = {vzero, vzero, vzero, vzero};   // 64 tok x 16 experts

    const _Float16* const Wbp = spl ? W1l : W1h;
    const _Float16* const Xbp = spl ? Xl  : Xh;
    const size_t xbase = (size_t)blk * 192 * 128;

    _Float16* const myHh = (_Float16*)(smem + OFF_H + w * 9216);
    _Float16* const myHl = myHh + 2304;

    for (int jc = 0; jc < NJC; ++jc) {
        f32x4 acc1[4][8];
        #pragma unroll
        for (int tf = 0; tf < 4; ++tf)
            #pragma unroll
            for (int jf = 0; jf < 8; ++jf) acc1[tf][jf] = vzero;

        // ---- prologue: stage it=0 into buf0 (A: 2 gload16, B: 8 gload16)
        {
            const _Float16* asrc = Xbp + (xbase + (size_t)sko * 128) * 8;
            char* adst = smem + OFF_A + spl * 8192 + sko * 2048;
            gload16(asrc + (size_t)lane * 8, adst);
            gload16(asrc + (size_t)(64 + lane) * 8, adst + 1024);
            const _Float16* bsrc = Wbp + ((size_t)sko * JD + jc * BJ) * 8;
            char* bdst = smem + OFF_B + spl * 32768 + sko * 8192;
            #pragma unroll
            for (int q = 0; q < 8; ++q)
                gload16(bsrc + (size_t)(q * 64 + lane) * 8, bdst + q * 1024);
        }
        __syncthreads();

        for (int it = 0; it < NIT; ++it) {
            const int cur = it & 1, nxt = cur ^ 1;
            const bool more = (it + 1 < NIT);
            if (more) {   // stage it+1 (zero-VALU gload16 path)
                const _Float16* asrc = Xbp + (xbase + (size_t)((it + 1) * 4 + sko) * 128) * 8;
                char* adst = smem + OFF_A + nxt * SZ_A + spl * 8192 + sko * 2048;
                gload16(asrc + (size_t)lane * 8, adst);
                gload16(asrc + (size_t)(64 + lane) * 8, adst + 1024);
                const _Float16* bsrc = Wbp +
                    ((size_t)((it + 1) * 4 + sko) * JD + jc * BJ) * 8;
                char* bdst = smem + OFF_B + nxt * SZ_B + spl * 32768 + sko * 8192;
                #pragma unroll
                for (int q = 0; q < 8; ++q)
                    gload16(bsrc + (size_t)(q * 64 + lane) * 8, bdst + q * 1024);
            }
            const char* ab = smem + OFF_A + cur * SZ_A;
            const char* bb = smem + OFF_B + cur * SZ_B;
            half8 ah[4], al[4];
            #pragma unroll
            for (int tf = 0; tf < 4; ++tf) {
                ah[tf] = *(const half8*)(ab + aoff[tf]);
                al[tf] = *(const half8*)(ab + 8192 + aoff[tf]);
            }
            #pragma unroll
            for (int jf = 0; jf < 8; ++jf) {   // per-jf B loads keep pressure low
                half8 bh = *(const half8*)(bb + boff[jf]);
                half8 bl = *(const half8*)(bb + 32768 + boff[jf]);
                #pragma unroll
                for (int tf = 0; tf < 4; ++tf) {
                    acc1[tf][jf] = mfma16(ah[tf], bh, acc1[tf][jf]);
                    acc1[tf][jf] = mfma16(ah[tf], bl, acc1[tf][jf]);
                    acc1[tf][jf] = mfma16(al[tf], bh, acc1[tf][jf]);
                }
            }
            __syncthreads();   // drains it+1 gloads (issued a full iter ago)
        }

        // ---- GELU + expert-split GEMM2: 4 rounds of 32-j chunks per wave
        #pragma unroll
        for (int r = 0; r < 4; ++r) {
            #pragma unroll
            for (int c = 0; c < 2; ++c) {
                const int jf = 2*r + c;
                #pragma unroll
                for (int tf = 0; tf < 4; ++tf)
                    #pragma unroll
                    for (int rr = 0; rr < 4; ++rr) {
                        const float v = acc1[tf][jf][rr];
                        const float gv = 0.5f * v * (1.0f + erff(v * 0.70710678118654752f));
                        const _Float16 gh = (_Float16)gv;
                        const _Float16 gl = (_Float16)(gv - (float)gh);
                        const int o = (tf*16 + lg*4 + rr) * HS + c*16 + l15;
                        myHh[o] = gh; myHl[o] = gl;
                    }
            }
            __syncthreads();
            #pragma unroll
            for (int s = 0; s < 4; ++s) {
                const _Float16* sh = (const _Float16*)(smem + OFF_H + (tg*4 + s) * 9216);
                const _Float16* sl = sh + 2304;
                const int jo = jc*64 + s*16 + r*4 + lg;
                const size_t wg = ((size_t)jo * 64 + jg*16 + l15) * 8;
                half8 b2h = *(const half8*)(W2h + wg);
                half8 b2l = *(const half8*)(W2l + wg);
                #pragma unroll
                for (int tf = 0; tf < 4; ++tf) {
                    const int o = (tf*16 + l15) * HS + lg*8;
                    half8 a2h = *(const half8*)(sh + o);
                    half8 a2l = *(const half8*)(sl + o);
                    lacc[tf] = mfma16(a2h, b2h, lacc[tf]);
                    lacc[tf] = mfma16(a2h, b2l, lacc[tf]);
                    lacc[tf] = mfma16(a2l, b2h, lacc[tf]);
                }
            }
            __syncthreads();
        }
    }

    // ---- epilogue
    float* const Lred = (float*)(smem + OFF_LRED);
    #pragma unroll
    for (int tf = 0; tf < 4; ++tf)
        #pragma unroll
        for (int rr = 0; rr < 4; ++rr)
            Lred[(tg*64 + tf*16 + lg*4 + rr) * 68 + jg*16 + l15] = lacc[tf][rr];
    __syncthreads();

    float* const mA   = (float*)(smem + OFF_EPI);
    float* const invA = mA + BM;
    int*   const i1A  = (int*)(invA + BM);
    int*   const i2A  = i1A + BM;
    float* const rp1A = (float*)(i2A + BM);
    float* const rp2A = rp1A + BM;

    if (tid < BM) {
        const float* row = Lred + tid * 68;
        float m = -3.402823466e38f;
        for (int e = 0; e < NE; ++e) m = fmaxf(m, row[e]);
        float s = 0.f, v1 = -3.402823466e38f, v2 = -3.402823466e38f;
        int i1 = 0, i2 = 0;
        for (int e = 0; e < NE; ++e) {
            const float v = row[e];
            s += expf(v - m);
            if (v > v1)      { v2 = v1; i2 = i1; v1 = v; i1 = e; }
            else if (v > v2) { v2 = v; i2 = e; }
        }
        const float inv = 1.f / s;
        const float p1 = fminf(expf(v1 - m) * inv + EPSV, 1.f - EPSV);
        const float p2 = fminf(expf(v2 - m) * inv + EPSV, 1.f - EPSV);
        mA[tid] = m; invA[tid] = inv; i1A[tid] = i1; i2A[tid] = i2;
        const float den = p1 + p2;
        rp1A[tid] = p1 / den; rp2A[tid] = p2 / den;
    }
    __syncthreads();

    for (int idx = tid; idx < BM * NE; idx += NTH) {
        const int r = idx >> 6, e = idx & 63;
        const size_t o = (size_t)(t0 + r) * NE + e;
        const float p = fminf(expf(Lred[r * 68 + e] - mA[r]) * invA[r] + EPSV, 1.f - EPSV);
        const int b1 = (e == i1A[r]), b2 = (e == i2A[r]);
        out_probs[o] = p;
        out_mask[o]  = (b1 | b2) ? 1.f : 0.f;
        out_rp[o]    = b1 ? rp1A[r] : (b2 ? rp2A[r] : 0.f);
    }
    if (tid < BM * 2) {
        const int r = tid >> 1, q = tid & 1;
        out_topi[(size_t)(t0 + r) * 2 + q] = (float)(q ? i2A[r] : i1A[r]);
    }
}

// ================= r9-style fallback (ws-small path, r16-proven) =================
#define FB_SZ_A  16384
#define FB_SZ_B  32768
#define FB_OFF_B 32768
#define FB_LDS   98304

__global__ __launch_bounds__(NTH, 1)
void router_v9fb(const float* __restrict__ inp, const float* __restrict__ cnd,
                 const _Float16* __restrict__ W1h, const _Float16* __restrict__ W1l,
                 const _Float16* __restrict__ W2h, const _Float16* __restrict__ W2l,
                 float* __restrict__ out_mask, float* __restrict__ out_topi,
                 float* __restrict__ out_rp, float* __restrict__ out_probs)
{
    __shared__ __align__(16) char smem[FB_LDS];
    const int tid  = threadIdx.x;
    const int lane = tid & 63;
    const int w    = tid >> 6;
    const int tg   = w >> 2;
    const int jg   = w & 3;
    const int l15  = lane & 15;
    const int lg   = lane >> 4;
    const int t0   = blockIdx.x * BM;
    const int akoct = w >> 1;
    const int arow  = (w & 1) * 64 + lane;
    const int bplane = w >> 2;
    const int bkoct  = w & 3;

    int aoff[4], boff[4];
    #pragma unroll
    for (int tf = 0; tf < 4; ++tf) aoff[tf] = (lg*128 + tg*64 + tf*16 + l15) * 16;
    #pragma unroll
    for (int jf = 0; jf < 4; ++jf) boff[jf] = (lg*256 + jg*64 + jf*16 + l15) * 16;

    const f32x4 vzero = {0.f, 0.f, 0.f, 0.f};
    f32x4 lacc[4] = {vzero, vzero, vzero, vzero};
    const float* const xrowA = inp + (size_t)(t0 + arow) * D0;
    const float* const xrowC = cnd + (size_t)(t0 + arow) * DCC;
    const _Float16* const Wbp = bplane ? W1l : W1h;
    _Float16* const myHh = (_Float16*)(smem + w * 9216);
    _Float16* const myHl = myHh + 2304;

    for (int jc = 0; jc < JD/256; ++jc) {
        f32x4 acc1[4][4];
        #pragma unroll
        for (int tf = 0; tf < 4; ++tf)
            #pragma unroll
            for (int jf = 0; jf < 4; ++jf) acc1[tf][jf] = vzero;
        {
            #pragma unroll
            for (int q = 0; q < 4; ++q) {
                const _Float16* src = Wbp + ((size_t)bkoct * JD + jc*256 + q*64 + lane) * 8;
                gload16(src, smem + FB_OFF_B + bplane*16384 + bkoct*4096 + q*1024);
            }
            const float* sx = xrowA + akoct * 8;
            float4 v0 = *(const float4*)sx;
            float4 v1 = *(const float4*)(sx + 4);
            half8 hh, hl;
            split8(v0, v1, hh, hl);
            const int g = (akoct*128 + arow) * 16;
            *(half8*)(smem + g) = hh;
            *(half8*)(smem + 8192 + g) = hl;
        }
        __syncthreads();
        for (int it = 0; it < NIT; ++it) {
            const int cur = it & 1, nxt = cur ^ 1;
            const bool more = (it + 1 < NIT);
            float4 xv0, xv1;
            if (more) {
                const int ko = (it + 1) * 4 + bkoct;
                #pragma unroll
                for (int q = 0; q < 4; ++q) {
                    const _Float16* src = Wbp + ((size_t)ko * JD + jc*256 + q*64 + lane) * 8;
                    gload16(src, smem + FB_OFF_B + nxt*FB_SZ_B + bplane*16384 + bkoct*4096 + q*1024);
                }
                const int k = (it + 1) * 32 + akoct * 8;
                const float* sx = (k < D0) ? (xrowA + k) : (xrowC + k - D0);
                xv0 = *(const float4*)sx;
                xv1 = *(const float4*)(sx + 4);
            }
            const char* ab = smem + cur*FB_SZ_A;
            const char* bb = smem + FB_OFF_B + cur*FB_SZ_B;
            half8 ah[4], al[4], bh[4], bl[4];
            #pragma unroll
            for (int tf = 0; tf < 4; ++tf) {
                ah[tf] = *(const half8*)(ab + aoff[tf]);
                al[tf] = *(const half8*)(ab + 8192 + aoff[tf]);
            }
            #pragma unroll
            for (int jf = 0; jf < 4; ++jf) {
                bh[jf] = *(const half8*)(bb + boff[jf]);
                bl[jf] = *(const half8*)(bb + 16384 + boff[jf]);
            }
            #pragma unroll
            for (int tf = 0; tf < 4; ++tf)
                #pragma unroll
                for (int jf = 0; jf < 4; ++jf) {
                    acc1[tf][jf] = mfma16(ah[tf], bh[jf], acc1[tf][jf]);
                    acc1[tf][jf] = mfma16(ah[tf], bl[jf], acc1[tf][jf]);
                    acc1[tf][jf] = mfma16(al[tf], bh[jf], acc1[tf][jf]);
                }
            if (more) {
                half8 hh, hl;
                split8(xv0, xv1, hh, hl);
                const int g = (akoct*128 + arow) * 16;
                *(half8*)(smem + nxt*FB_SZ_A + g) = hh;
                *(half8*)(smem + nxt*FB_SZ_A + 8192 + g) = hl;
            }
            __syncthreads();
        }
        #pragma unroll
        for (int r = 0; r < 2; ++r) {
            #pragma unroll
            for (int c = 0; c < 2; ++c) {
                const int jf = 2*r + c;
                #pragma unroll
                for (int tf = 0; tf < 4; ++tf)
                    #pragma unroll
                    for (int rr = 0; rr < 4; ++rr) {
                        const float v = acc1[tf][jf][rr];
                        const float gv = 0.5f * v * (1.0f + erff(v * 0.70710678118654752f));
                        const _Float16 gh = (_Float16)gv;
                        const _Float16 gl = (_Float16)(gv - (float)gh);
                        const int o = (tf*16 + lg*4 + rr) * HS + c*16 + l15;
                        myHh[o] = gh; myHl[o] = gl;
                    }
            }
            __syncthreads();
            #pragma unroll
            for (int s = 0; s < 4; ++s) {
                const _Float16* sh = (const _Float16*)(smem + (tg*4 + s) * 9216);
                const _Float16* sl = sh + 2304;
                const int jo = jc*32 + s*8 + r*4 + lg;
                const size_t wg = ((size_t)jo * 64 + jg*16 + l15) * 8;
                half8 b2h = *(const half8*)(W2h + wg);
                half8 b2l = *(const half8*)(W2l + wg);
                #pragma unroll
                for (int tf = 0; tf < 4; ++tf) {
                    const int o = (tf*16 + l15) * HS + lg*8;
                    half8 a2h = *(const half8*)(sh + o);
                    half8 a2l = *(const half8*)(sl + o);
                    lacc[tf] = mfma16(a2h, b2h, lacc[tf]);
                    lacc[tf] = mfma16(a2h, b2l, lacc[tf]);
                    lacc[tf] = mfma16(a2l, b2h, lacc[tf]);
                }
            }
            __syncthreads();
        }
    }
    float* const Lred = (float*)smem;
    #pragma unroll
    for (int tf = 0; tf < 4; ++tf)
        #pragma unroll
        for (int rr = 0; rr < 4; ++rr)
            Lred[(tg*64 + tf*16 + lg*4 + rr) * 68 + jg*16 + l15] = lacc[tf][rr];
    __syncthreads();
    float* const mA   = (float*)(smem + 36864);
    float* const invA = mA + BM;
    int*   const i1A  = (int*)(invA + BM);
    int*   const i2A  = i1A + BM;
    float* const rp1A = (float*)(i2A + BM);
    float* const rp2A = rp1A + BM;
    if (tid < BM) {
        const float* row = Lred + tid * 68;
        float m = -3.402823466e38f;
        for (int e = 0; e < NE; ++e) m = fmaxf(m, row[e]);
        float s = 0.f, v1 = -3.402823466e38f, v2 = -3.402823466e38f;
        int i1 = 0, i2 = 0;
        for (int e = 0; e < NE; ++e) {
            const float v = row[e];
            s += expf(v - m);
            if (v > v1)      { v2 = v1; i2 = i1; v1 = v; i1 = e; }
            else if (v > v2) { v2 = v; i2 = e; }
        }
        const float inv = 1.f / s;
        const float p1 = fminf(expf(v1 - m) * inv + EPSV, 1.f - EPSV);
        const float p2 = fminf(expf(v2 - m) * inv + EPSV, 1.f - EPSV);
        mA[tid] = m; invA[tid] = inv; i1A[tid] = i1; i2A[tid] = i2;
        const float den = p1 + p2;
        rp1A[tid] = p1 / den; rp2A[tid] = p2 / den;
    }
    __syncthreads();
    for (int idx = tid; idx < BM * NE; idx += NTH) {
        const int r = idx >> 6, e = idx & 63;
        const size_t o = (size_t)(t0 + r) * NE + e;
        const float p = fminf(expf(Lred[r * 68 + e] - mA[r]) * invA[r] + EPSV, 1.f - EPSV);
        const int b1 = (e == i1A[r]), b2 = (e == i2A[r]);
        out_probs[o] = p;
        out_mask[o]  = (b1 | b2) ? 1.f : 0.f;
        out_rp[o]    = b1 ? rp1A[r] : (b2 ? rp2A[r] : 0.f);
    }
    if (tid < BM * 2) {
        const int r = tid >> 1, q = tid & 1;
        out_topi[(size_t)(t0 + r) * 2 + q] = (float)(q ? i2A[r] : i1A[r]);
    }
}

extern "C" void kernel_launch(void* const* d_in, const int* in_sizes, int n_in,
                              void* d_out, int out_size, void* d_ws, size_t ws_size,
                              hipStream_t stream) {
    const float* inp = (const float*)d_in[0];
    const float* cnd = (const float*)d_in[1];
    const float* W1  = (const float*)d_in[2];
    const float* W2  = (const float*)d_in[3];

    float* out = (float*)d_out;
    const size_t NT = (size_t)N_TOK;
    float* out_mask  = out;
    float* out_topi  = out + NT * NE;
    float* out_rp    = out + NT * NE + NT * 2;
    float* out_probs = out + NT * NE + NT * 2 + NT * NE;

    const size_t V17_REQ = (2*XTN + 2*W1N + 2*W2N) * 2;   // ~221 MB
    if (ws_size >= V17_REQ) {
        _Float16* Xh  = (_Float16*)d_ws;
        _Float16* Xl  = Xh + XTN;
        _Float16* W1h = Xl + XTN;
        _Float16* W1l = W1h + W1N;
        _Float16* W2h = W1l + W1N;
        _Float16* W2l = W2h + W2N;
        hipLaunchKernelGGL(presplit_xt,  dim3(XT_G/256), dim3(256), 0, stream, inp, cnd, Xh, Xl);
        hipLaunchKernelGGL(presplit_w1t, dim3((W1T_G + 255)/256), dim3(256), 0, stream, W1, W1h, W1l);
        hipLaunchKernelGGL(presplit_w2t, dim3((W2T_G + 255)/256), dim3(256), 0, stream, W2, W2h, W2l);
        hipLaunchKernelGGL(router_v17, dim3(N_TOK / BM), dim3(NTH), 0, stream,
                           Xh, Xl, W1h, W1l, W2h, W2l,
                           out_mask, out_topi, out_rp, out_probs);
    } else {
        _Float16* W1h = (_Float16*)d_ws;
        _Float16* W1l = W1h + W1N;
        _Float16* W2h = W1l + W1N;
        _Float16* W2l = W2h + W2N;
        hipLaunchKernelGGL(presplit_w1t, dim3((W1T_G + 255)/256), dim3(256), 0, stream, W1, W1h, W1l);
        hipLaunchKernelGGL(presplit_w2t, dim3((W2T_G + 255)/256), dim3(256), 0, stream, W2, W2h, W2l);
        hipLaunchKernelGGL(router_v9fb, dim3(N_TOK / BM), dim3(NTH), 0, stream,
                           inp, cnd, W1h, W1l, W2h, W2l,
                           out_mask, out_topi, out_rp, out_probs);
    }
}